// Round 5
// baseline (309.930 us; speedup 1.0000x reference)
//
#include <hip/hip_runtime.h>

// MultiHeadedAttention B=8,S=1024,D=1024,H=16,dk=64 — bf16 MFMA pipeline.
// R5: V-projection GEMM writes its output TRANSPOSED (Vt[(b*16+h)*64+dk][s])
// directly via an LDS-staged epilogue — transp_v kernel eliminated.
// Pipeline: cvt_all -> gemm_qkv(Q,K row-major; V transposed) -> attn_mfma
// (32x32x16, in-register C->A P transform) -> gemm_dense.
// Scale 1/8 folded into wq/bq. p = exp(s')*pol; x = sum(p*v)/(sum p + EPS).

#define Sdim 1024
#define Ddim 1024

typedef unsigned short u16;
typedef float f32x4 __attribute__((ext_vector_type(4)));
typedef float f32x16 __attribute__((ext_vector_type(16)));
typedef __bf16 bf16x8 __attribute__((ext_vector_type(8)));
typedef u16 u16x8 __attribute__((ext_vector_type(8)));
typedef __attribute__((address_space(3))) void lds_void;
typedef __attribute__((address_space(1))) void gbl_void;

__device__ __forceinline__ u16 f2bf(float f) {
    unsigned u = __float_as_uint(f);
    u += 0x7fffu + ((u >> 16) & 1u);   // RNE
    return (u16)(u >> 16);
}
__device__ __forceinline__ void gld16(const void* g, void* l) {
    __builtin_amdgcn_global_load_lds((const gbl_void*)g, (lds_void*)l, 16, 0, 0);
}
// pack two f32 -> two bf16 (round-half-up) in one u32 via v_perm
__device__ __forceinline__ unsigned pk_bf16(float lo, float hi) {
    const unsigned ul = __float_as_uint(lo) + 0x8000u;
    const unsigned uh = __float_as_uint(hi) + 0x8000u;
    return __builtin_amdgcn_perm(uh, ul, 0x07060302u);
}
#define MFMA16(a, b, c) __builtin_amdgcn_mfma_f32_16x16x32_bf16((a), (b), (c), 0, 0, 0)
#define MFMA32(a, b, c) __builtin_amdgcn_mfma_f32_32x32x16_bf16((a), (b), (c), 0, 0, 0)

// ---------------------------------------------------------------------------
// fused fp32->bf16 converts; y=0..2 activations (8M), y=3..6 weights (1M).
// y==3 (wq) is scaled by 0.125 (folds 1/sqrt(dk) into the Q projection).
// ---------------------------------------------------------------------------
__global__ __launch_bounds__(256) void cvt_all(const float* __restrict__ s0,
                                               const float* __restrict__ s1,
                                               const float* __restrict__ s2,
                                               const float* __restrict__ s3,
                                               const float* __restrict__ s4,
                                               const float* __restrict__ s5,
                                               const float* __restrict__ s6,
                                               u16* __restrict__ d0, u16* __restrict__ d1,
                                               u16* __restrict__ d2, u16* __restrict__ d3,
                                               u16* __restrict__ d4, u16* __restrict__ d5,
                                               u16* __restrict__ d6) {
    const int z = blockIdx.y;
    if (z >= 3 && blockIdx.x >= 512) return;
    const float* s = z == 0 ? s0 : z == 1 ? s1 : z == 2 ? s2 : z == 3 ? s3
                   : z == 4 ? s4 : z == 5 ? s5 : s6;
    u16* d = z == 0 ? d0 : z == 1 ? d1 : z == 2 ? d2 : z == 3 ? d3
           : z == 4 ? d4 : z == 5 ? d5 : d6;
    const float sc = (z == 3) ? 0.125f : 1.0f;
    const int i = (blockIdx.x * 256 + threadIdx.x) * 8;
    const float4 a = *(const float4*)(s + i);
    const float4 b = *(const float4*)(s + i + 4);
    u16x8 o;
    o[0] = f2bf(a.x * sc); o[1] = f2bf(a.y * sc); o[2] = f2bf(a.z * sc); o[3] = f2bf(a.w * sc);
    o[4] = f2bf(b.x * sc); o[5] = f2bf(b.y * sc); o[6] = f2bf(b.z * sc); o[7] = f2bf(b.w * sc);
    *(u16x8*)(d + i) = o;
}

// ---------------------------------------------------------------------------
// GEMM core: C[M][1024] = A[M][1024] @ W[1024][1024]^T + bias*bscale
// m97 structure, 128x128 tile, BK=32, 16x16x32 MFMA.
// MODE 0: bf16 row-major out. MODE 1: fp32 row-major out.
// MODE 2: bf16 TRANSPOSED out -> Vt[(b*16+h)*64+dk][s] (V projection).
// ---------------------------------------------------------------------------
template <int MODE>
__device__ __forceinline__ void gemm_core(const u16* __restrict__ A,
                                          const u16* __restrict__ W,
                                          const float* __restrict__ bias, float bscale,
                                          void* __restrict__ Cout,
                                          u16* sbuf, int m0, int n0) {
    u16* As = sbuf;
    u16* Bs = sbuf + 4096;
    const int tid  = threadIdx.x;
    const int wave = tid >> 6;
    const int lane = tid & 63;
    const int l15  = lane & 15;
    const int quad = lane >> 4;
    const int wm = (wave >> 1) * 64;
    const int wn = (wave & 1) * 64;

    const int e0 = wave * 512 + lane * 8;
    const int r0 = e0 >> 5, c0 = e0 & 31;
    const int e1 = 2048 + e0;
    const int r1 = e1 >> 5, c1 = e1 & 31;
    const u16* Ag0 = A + (size_t)(m0 + r0) * Ddim + c0;
    const u16* Ag1 = A + (size_t)(m0 + r1) * Ddim + c1;
    const u16* Wg0 = W + (size_t)(n0 + r0) * Ddim + c0;
    const u16* Wg1 = W + (size_t)(n0 + r1) * Ddim + c1;
    u16* As0 = As + wave * 512;
    u16* As1 = As + 2048 + wave * 512;
    u16* Bs0 = Bs + wave * 512;
    u16* Bs1 = Bs + 2048 + wave * 512;

    f32x4 acc[4][4] = {};

    for (int k0 = 0; k0 < Ddim; k0 += 32) {
        __syncthreads();
        gld16(Ag0 + k0, As0);
        gld16(Ag1 + k0, As1);
        gld16(Wg0 + k0, Bs0);
        gld16(Wg1 + k0, Bs1);
        __syncthreads();
        bf16x8 af[4], bfr[4];
#pragma unroll
        for (int i = 0; i < 4; ++i)
            af[i] = *(const bf16x8*)(As + (wm + i * 16 + l15) * 32 + quad * 8);
#pragma unroll
        for (int j = 0; j < 4; ++j)
            bfr[j] = *(const bf16x8*)(Bs + (wn + j * 16 + l15) * 32 + quad * 8);
#pragma unroll
        for (int i = 0; i < 4; ++i)
#pragma unroll
            for (int j = 0; j < 4; ++j)
                acc[i][j] = MFMA16(af[i], bfr[j], acc[i][j]);
    }

    float bv[4];
#pragma unroll
    for (int j = 0; j < 4; ++j) bv[j] = bias[n0 + wn + j * 16 + l15] * bscale;

    if (MODE == 2) {
        // ---- transposed-V epilogue: stage C tile in LDS, write Vt ----
        __syncthreads();                 // all waves done reading As/Bs
        u16* Ts = sbuf;                  // [128][136] u16 = 34816 B
#pragma unroll
        for (int i = 0; i < 4; ++i)
#pragma unroll
            for (int j = 0; j < 4; ++j)
#pragma unroll
                for (int r = 0; r < 4; ++r)
                    Ts[(wm + i * 16 + quad * 4 + r) * 136 + wn + j * 16 + l15] =
                        f2bf(acc[i][j][r] + bv[j]);
        __syncthreads();
        const int orow = tid >> 1;       // 0..127 output row within this tile
        const int p    = orow >> 6;      // head-half within the 128-col n-block
        const int dkl  = orow & 63;      // dk within head
        const int sh   = (tid & 1) * 64; // s-half
        const int bidx = m0 >> 10;       // batch (tiles never straddle b)
        const int s0   = m0 & 1023;
        const int h    = (n0 >> 6) + p;
        u16* dst = (u16*)Cout + ((size_t)((bidx * 16 + h) * 64 + dkl)) * Sdim + s0 + sh;
#pragma unroll
        for (int g = 0; g < 8; ++g) {
            u16x8 o;
#pragma unroll
            for (int j8 = 0; j8 < 8; ++j8)
                o[j8] = Ts[(sh + g * 8 + j8) * 136 + p * 64 + dkl];
            *(u16x8*)(dst + g * 8) = o;
        }
    } else {
#pragma unroll
        for (int i = 0; i < 4; ++i)
#pragma unroll
            for (int j = 0; j < 4; ++j)
#pragma unroll
                for (int r = 0; r < 4; ++r) {
                    const int row = m0 + wm + i * 16 + quad * 4 + r;
                    const int col = n0 + wn + j * 16 + l15;
                    const float v = acc[i][j][r] + bv[j];
                    if (MODE == 0)
                        ((u16*)Cout)[(size_t)row * Ddim + col] = f2bf(v);
                    else
                        ((float*)Cout)[(size_t)row * Ddim + col] = v;
                }
    }
}

// fused QKV projection: z=0 -> Qp (bias*0.125), z=1 -> Kp, z=2 -> Vt (transposed)
__global__ __launch_bounds__(256) void gemm_qkv(const u16* __restrict__ A0, const u16* __restrict__ A1,
                                                const u16* __restrict__ A2,
                                                const u16* __restrict__ W0, const u16* __restrict__ W1,
                                                const u16* __restrict__ W2,
                                                const float* __restrict__ b0, const float* __restrict__ b1,
                                                const float* __restrict__ b2,
                                                u16* __restrict__ Qp, u16* __restrict__ Kp,
                                                u16* __restrict__ Vt) {
    __shared__ __align__(16) u16 sbuf[17408];   // k-loop: As+Bs (16 KB); V-epi: Ts (34 KB)
    const int z = blockIdx.z;
    const int m0 = blockIdx.x * 128, n0 = blockIdx.y * 128;
    if (z == 2) {
        gemm_core<2>(A2, W2, b2, 1.0f, (void*)Vt, sbuf, m0, n0);
    } else {
        const u16* A = z ? A1 : A0;
        const u16* W = z ? W1 : W0;
        const float* bias = z ? b1 : b0;
        u16* C = z ? Kp : Qp;
        gemm_core<0>(A, W, bias, z ? 1.0f : 0.125f, (void*)C, sbuf, m0, n0);
    }
}

__global__ __launch_bounds__(256) void gemm_dense(const u16* __restrict__ A,
                                                  const u16* __restrict__ W,
                                                  const float* __restrict__ bias,
                                                  float* __restrict__ C) {
    __shared__ __align__(16) u16 sbuf[8192];
    gemm_core<1>(A, W, bias, 1.0f, (void*)C, sbuf, blockIdx.x * 128, blockIdx.y * 128);
}

// ---------------------------------------------------------------------------
// Attention on 32x32x16 MFMA. Block = 256 q-rows of one (b,h); wave owns 64 q.
// Per 64-kpos tile: S^T = K.Q^T (A=K-frag, B=Q-frag cached in regs);
// p = exp(s)*pol in f32; P regs re-laid C->A via shfl_xor(32)+cndmask;
// X += P.V^T. All LDS tiles stride 72 u16 (conflict-free for 32-row frags).
// ---------------------------------------------------------------------------
__global__ __launch_bounds__(256, 2) void attn_mfma(const u16* __restrict__ Qp,
                                                    const u16* __restrict__ Kp,
                                                    const u16* __restrict__ Vt,
                                                    const float* __restrict__ pol,
                                                    u16* __restrict__ Xb) {
    __shared__ __align__(16) u16 lds[28288];    // 56576 B
    u16* Qs = lds;                              // 256 x 72  (later: Xout)
    u16* Ks = lds + 18432;                      // 64 x 72   K[kpos][dk]
    u16* Vs = lds + 23040;                      // 64 x 72   V^T[d][kpos]
    float* pols = (float*)(lds + 27648);        // [64]
    float* denb = pols + 64;                    // [256] inv-den

    const int tid  = threadIdx.x;
    const int w    = tid >> 6;
    const int lane = tid & 63;
    const int l31  = lane & 31;
    const unsigned hsel = lane >> 5;            // half selector
    const int q0 = blockIdx.x * 256;
    const int bh = blockIdx.y;
    const size_t bS = (size_t)(bh >> 4) * Sdim;
    const int col0 = (bh & 15) * 64;
    const int sr = tid >> 2;                    // staging row 0..63
    const int sc4 = tid & 3;                    // staging chunk base

    // ---- stage Q tile 256x64 and load Q B-frags into registers ----
#pragma unroll
    for (int rg = 0; rg < 4; ++rg) {
        const int r = rg * 64 + sr;
#pragma unroll
        for (int g = 0; g < 2; ++g) {
            const int ch = sc4 + g * 4;
            *(u16x8*)(Qs + r * 72 + ch * 8) =
                *(const u16x8*)(Qp + (bS + q0 + r) * Ddim + col0 + ch * 8);
        }
    }
    __syncthreads();
    bf16x8 Qf[2][4];
#pragma unroll
    for (int qt = 0; qt < 2; ++qt)
#pragma unroll
        for (int dkt = 0; dkt < 4; ++dkt)
            Qf[qt][dkt] = *(const bf16x8*)(Qs + (w * 64 + qt * 32 + l31) * 72 +
                                           dkt * 16 + hsel * 8);

    f32x16 X[2][2] = {};
    float den[2] = {0.f, 0.f};

    for (int kt = 0; kt < 16; ++kt) {
        const int kbase = kt * 64;
        __syncthreads();
        // stage K[64][64] and V^T[64][64]
#pragma unroll
        for (int g = 0; g < 2; ++g) {
            const int ch = sc4 + g * 4;
            *(u16x8*)(Ks + sr * 72 + ch * 8) =
                *(const u16x8*)(Kp + (bS + kbase + sr) * Ddim + col0 + ch * 8);
            *(u16x8*)(Vs + sr * 72 + ch * 8) =
                *(const u16x8*)(Vt + ((size_t)(bh * 64 + sr)) * Sdim + kbase + ch * 8);
        }
        if (tid < 64) pols[tid] = pol[bS + kbase + tid];
        __syncthreads();

#pragma unroll
        for (int t32 = 0; t32 < 2; ++t32) {
            // pol per C-layout row (broadcast reads; uniform per (e,half))
            float polv[16];
#pragma unroll
            for (int e = 0; e < 16; ++e)
                polv[e] = pols[t32 * 32 + (e & 3) + 8 * (e >> 2) + 4 * hsel];
            bf16x8 Kf[4];
#pragma unroll
            for (int dkt = 0; dkt < 4; ++dkt)
                Kf[dkt] = *(const bf16x8*)(Ks + (t32 * 32 + l31) * 72 +
                                           dkt * 16 + hsel * 8);
#pragma unroll
            for (int qt = 0; qt < 2; ++qt) {
                f32x16 S = {};
#pragma unroll
                for (int dkt = 0; dkt < 4; ++dkt)
                    S = MFMA32(Kf[dkt], Qf[qt][dkt], S);   // D[kpos][q]
                // softmax numerator (f32), accumulate den per-lane (q = l31)
                float p[16];
#pragma unroll
                for (int e = 0; e < 16; ++e) {
                    p[e] = __expf(S[e]) * polv[e];
                    den[qt] += p[e];
                }
                // pack pairs along kpos rows
                unsigned pk_[8], sw[8];
#pragma unroll
                for (int g = 0; g < 4; ++g) {
                    pk_[2 * g]     = pk_bf16(p[4 * g + 0], p[4 * g + 1]);
                    pk_[2 * g + 1] = pk_bf16(p[4 * g + 2], p[4 * g + 3]);
                }
#pragma unroll
                for (int i = 0; i < 8; ++i)
                    sw[i] = (unsigned)__shfl_xor((int)pk_[i], 32);
                // P A-frags for the two 16-k tiles of this 32-kpos block
#pragma unroll
                for (int tau = 0; tau < 2; ++tau) {
                    union { unsigned u[4]; bf16x8 v; } Af;
                    Af.u[0] = hsel ? sw[(2 * tau + 1) * 2 + 0] : pk_[(2 * tau) * 2 + 0];
                    Af.u[1] = hsel ? sw[(2 * tau + 1) * 2 + 1] : pk_[(2 * tau) * 2 + 1];
                    Af.u[2] = hsel ? pk_[(2 * tau + 1) * 2 + 0] : sw[(2 * tau) * 2 + 0];
                    Af.u[3] = hsel ? pk_[(2 * tau + 1) * 2 + 1] : sw[(2 * tau) * 2 + 1];
#pragma unroll
                    for (int ndt = 0; ndt < 2; ++ndt) {
                        const bf16x8 Vf =
                            *(const bf16x8*)(Vs + (ndt * 32 + l31) * 72 +
                                             t32 * 32 + tau * 16 + hsel * 8);
                        X[qt][ndt] = MFMA32(Af.v, Vf, X[qt][ndt]);  // D[q][d]
                    }
                }
            }
        }
    }

    // ---- epilogue: den reduce, normalize, stage to LDS, coalesced store ----
#pragma unroll
    for (int qt = 0; qt < 2; ++qt) {
        den[qt] += __shfl_xor(den[qt], 32);
        denb[w * 64 + qt * 32 + l31] = 1.0f / (den[qt] + 1e-6f);
    }
    u16* Xout = Qs;   // Q frags live in regs; Qs region reused
#pragma unroll
    for (int qt = 0; qt < 2; ++qt) {
        float invv[16];
#pragma unroll
        for (int e = 0; e < 16; ++e)
            invv[e] = denb[w * 64 + qt * 32 + (e & 3) + 8 * (e >> 2) + 4 * hsel];
#pragma unroll
        for (int ndt = 0; ndt < 2; ++ndt)
#pragma unroll
            for (int e = 0; e < 16; ++e) {
                const int rho = (e & 3) + 8 * (e >> 2) + 4 * hsel;
                Xout[(w * 64 + qt * 32 + rho) * 72 + ndt * 32 + l31] =
                    f2bf(X[qt][ndt][e] * invv[e]);
            }
    }
    __syncthreads();
#pragma unroll
    for (int rg = 0; rg < 4; ++rg) {
        const int r = rg * 64 + sr;
#pragma unroll
        for (int g = 0; g < 2; ++g) {
            const int ch = sc4 + g * 4;
            *(u16x8*)(Xb + (bS + q0 + r) * Ddim + col0 + ch * 8) =
                *(const u16x8*)(Xout + r * 72 + ch * 8);
        }
    }
}

// ---------------------------------------------------------------------------
extern "C" void kernel_launch(void* const* d_in, const int* in_sizes, int n_in,
                              void* d_out, int out_size, void* d_ws, size_t ws_size,
                              hipStream_t stream) {
    const float* query   = (const float*)d_in[0];
    const float* key     = (const float*)d_in[1];
    const float* value   = (const float*)d_in[2];
    const float* policy  = (const float*)d_in[3];
    const float* wq_w    = (const float*)d_in[4];
    const float* wq_b    = (const float*)d_in[5];
    const float* wk_w    = (const float*)d_in[6];
    const float* wk_b    = (const float*)d_in[7];
    const float* wv_w    = (const float*)d_in[8];
    const float* wv_b    = (const float*)d_in[9];
    const float* dense_w = (const float*)d_in[10];
    const float* dense_b = (const float*)d_in[11];

    const size_t MM = 1u << 20;
    const size_t A8 = 8 * MM;
    u16* qa  = (u16*)d_ws;        // later aliased as Xb
    u16* ka  = qa + A8;
    u16* va  = ka + A8;
    u16* wqb = va + A8;
    u16* wkb = wqb + MM;
    u16* wvb = wkb + MM;
    u16* wdb = wvb + MM;
    u16* Qp  = wdb + MM;
    u16* Kp  = Qp + A8;
    u16* Vtg = Kp + A8;           // V written here TRANSPOSED by gemm_qkv z==2
    u16* Xb  = qa;                // safe: qa consumed by gemm_qkv before attn

    cvt_all<<<dim3(4096, 7), 256, 0, stream>>>(query, key, value, wq_w, wk_w, wv_w, dense_w,
                                               qa, ka, va, wqb, wkb, wvb, wdb);

    gemm_qkv<<<dim3(64, 8, 3), 256, 0, stream>>>(qa, ka, va, wqb, wkb, wvb,
                                                 wq_b, wk_b, wv_b, Qp, Kp, Vtg);

    attn_mfma<<<dim3(4, 128), 256, 0, stream>>>(Qp, Kp, Vtg, policy, Xb);

    gemm_dense<<<dim3(64, 8), 256, 0, stream>>>(Xb, wdb, dense_b, (float*)d_out);
}